// Round 1
// baseline (240.428 us; speedup 1.0000x reference)
//
#include <hip/hip_runtime.h>
#include <cstddef>

#define B_  64
#define T_  2000
#define A_  256
#define K_  31
#define F_  32
#define TT_ 128   // t-rows per block (4 waves x 32 rows)
#define UR_ 4     // rows per inner iteration (keeps LDS window reads b128-aligned)

// tanh(x) = 1 - 2/(exp(2x)+1); saturates correctly for |x| large (rcp(inf)=0)
__device__ __forceinline__ float fast_tanh(float x) {
  float p = __expf(x + x);
  float r = __builtin_amdgcn_rcpf(p + 1.0f);
  return fmaf(-2.0f, r, 1.0f);
}

__device__ __forceinline__ float4 ld4(const float* p) {
  return *(const float4*)p;
}

// Fold conv_w*loc_w -> W2[k][a]; fold query+score_b+conv_b*loc_w -> qb[b][a]
__global__ __launch_bounds__(256) void prep_kernel(
    const float* __restrict__ conv_w, const float* __restrict__ conv_b,
    const float* __restrict__ loc_w, const float* __restrict__ query,
    const float* __restrict__ score_b, float* __restrict__ W2,
    float* __restrict__ qb) {
  const int a = threadIdx.x;
  const int blk = blockIdx.x;
  if (blk < K_) {
    float acc = 0.f;
    #pragma unroll
    for (int f = 0; f < F_; ++f) acc = fmaf(conv_w[blk * F_ + f], loc_w[f * A_ + a], acc);
    W2[blk * A_ + a] = acc;
  } else {
    const int b = blk - K_;
    float acc = 0.f;
    #pragma unroll
    for (int f = 0; f < F_; ++f) acc = fmaf(conv_b[f], loc_w[f * A_ + a], acc);
    qb[b * A_ + a] = query[b * A_ + a] + score_b[a] + acc;
  }
}

// energy[b][t] = sum_a v[a] * tanh( wmem[b][t][a] + qb[b][a] + sum_k pw[b][t+k-15]*W2[k][a] )
__global__ __launch_bounds__(256) void energy_kernel(
    const float* __restrict__ wmem, const float* __restrict__ pw,
    const float* __restrict__ qb, const float* __restrict__ W2,
    const float* __restrict__ score_v, float* __restrict__ energy) {
  const int b = blockIdx.y;
  const int t0 = blockIdx.x * TT_;
  const int lane = threadIdx.x & 63;
  const int wv = threadIdx.x >> 6;

  __shared__ __align__(16) float lds_pw[TT_ + 36];

  // stage the pw slice for this tile (index 0 == t0-15), zero-padded (SAME conv)
  if (threadIdx.x < TT_ + 36) {
    const int g = t0 - 15 + threadIdx.x;
    lds_pw[threadIdx.x] = (g >= 0 && g < T_) ? pw[b * T_ + g] : 0.f;
  }
  __syncthreads();

  // W2 columns for this lane's 4 a-values live in VGPRs (reused for all rows)
  float4 w2c[K_];
  #pragma unroll
  for (int k = 0; k < K_; ++k) w2c[k] = ld4(W2 + k * A_ + 4 * lane);
  const float4 qb4 = ld4(qb + b * A_ + 4 * lane);
  const float4 v4  = ld4(score_v + 4 * lane);

  const int rbase = 32 * wv;  // this wave's first row within the tile
  #pragma unroll 1
  for (int i = 0; i < 32 / UR_; ++i) {
    const int widx = rbase + UR_ * i;  // 4-aligned -> b128-aligned LDS reads
    float s[36];
    #pragma unroll
    for (int m = 0; m < 9; ++m) {
      const float4 t4 = ld4(&lds_pw[widx + 4 * m]);
      s[4 * m + 0] = t4.x; s[4 * m + 1] = t4.y;
      s[4 * m + 2] = t4.z; s[4 * m + 3] = t4.w;
    }
    #pragma unroll
    for (int j = 0; j < UR_; ++j) {
      const int t = t0 + widx + j;
      const int tc = t < T_ ? t : T_ - 1;  // clamp loads; store is predicated
      const float4 w4 = ld4(wmem + ((size_t)b * T_ + tc) * A_ + 4 * lane);
      float plx = 0.f, ply = 0.f, plz = 0.f, plw = 0.f;
      #pragma unroll
      for (int k = 0; k < K_; ++k) {
        const float sv = s[j + k];  // wave-uniform window scalar
        plx = fmaf(sv, w2c[k].x, plx);
        ply = fmaf(sv, w2c[k].y, ply);
        plz = fmaf(sv, w2c[k].z, plz);
        plw = fmaf(sv, w2c[k].w, plw);
      }
      const float tx = fast_tanh(w4.x + qb4.x + plx);
      const float ty = fast_tanh(w4.y + qb4.y + ply);
      const float tz = fast_tanh(w4.z + qb4.z + plz);
      const float tw = fast_tanh(w4.w + qb4.w + plw);
      float e = fmaf(v4.x, tx, fmaf(v4.y, ty, fmaf(v4.z, tz, v4.w * tw)));
      #pragma unroll
      for (int m = 1; m < 64; m <<= 1) e += __shfl_xor(e, m, 64);
      if (lane == 0 && t < T_) energy[b * T_ + t] = e;
    }
  }
}

// masked softmax over t + cumulative update; one block per batch row
__global__ __launch_bounds__(256) void softmax_kernel(
    const float* __restrict__ energy, const float* __restrict__ pw,
    const int* __restrict__ lens, float* __restrict__ out) {
  const int b = blockIdx.x;
  const int tid = threadIdx.x;
  const int len = lens[b];
  __shared__ float red[4];
  const float L2E = 1.4426950408889634f;

  // pass 1: max over valid t
  float mx = -3.4e38f;
  for (int t = tid; t < T_; t += 256)
    if (t < len) mx = fmaxf(mx, energy[b * T_ + t]);
  #pragma unroll
  for (int m = 1; m < 64; m <<= 1) mx = fmaxf(mx, __shfl_xor(mx, m, 64));
  if ((tid & 63) == 0) red[tid >> 6] = mx;
  __syncthreads();
  mx = fmaxf(fmaxf(red[0], red[1]), fmaxf(red[2], red[3]));
  __syncthreads();

  // pass 2: sum of exp
  float sm = 0.f;
  for (int t = tid; t < T_; t += 256)
    if (t < len) sm += __builtin_amdgcn_exp2f((energy[b * T_ + t] - mx) * L2E);
  #pragma unroll
  for (int m = 1; m < 64; m <<= 1) sm += __shfl_xor(sm, m, 64);
  if ((tid & 63) == 0) red[tid >> 6] = sm;
  __syncthreads();
  sm = red[0] + red[1] + red[2] + red[3];
  const float inv = 1.0f / sm;

  // pass 3: write output and new_weights
  for (int t = tid; t < T_; t += 256) {
    float o = 0.f;
    if (t < len)
      o = __builtin_amdgcn_exp2f((energy[b * T_ + t] - mx) * L2E) * inv;
    out[b * T_ + t] = o;
    out[B_ * T_ + b * T_ + t] = o + pw[b * T_ + t];
  }
}

extern "C" void kernel_launch(void* const* d_in, const int* in_sizes, int n_in,
                              void* d_out, int out_size, void* d_ws, size_t ws_size,
                              hipStream_t stream) {
  const float* query  = (const float*)d_in[0];
  const float* prev   = (const float*)d_in[1];
  const float* wmem   = (const float*)d_in[2];
  const int*   lens   = (const int*)d_in[3];
  const float* conv_w = (const float*)d_in[4];
  const float* conv_b = (const float*)d_in[5];
  const float* loc_w  = (const float*)d_in[6];
  const float* sv     = (const float*)d_in[7];
  const float* sb     = (const float*)d_in[8];
  float* out = (float*)d_out;
  float* ws  = (float*)d_ws;

  float* W2     = ws;                      // 31*256
  float* qb     = ws + K_ * A_;            // 64*256
  float* energy = ws + K_ * A_ + B_ * A_;  // 64*2000

  prep_kernel<<<K_ + B_, 256, 0, stream>>>(conv_w, conv_b, loc_w, query, sb, W2, qb);

  dim3 grid((T_ + TT_ - 1) / TT_, B_);  // 16 x 64
  energy_kernel<<<grid, 256, 0, stream>>>(wmem, prev, qb, W2, sv, energy);

  softmax_kernel<<<B_, 256, 0, stream>>>(energy, prev, lens, out);
}

// Round 2
// 228.298 us; speedup vs baseline: 1.0531x; 1.0531x over previous
//
#include <hip/hip_runtime.h>
#include <cstddef>

#define B_  64
#define T_  2000
#define A_  256
#define K_  31
#define F_  32
#define TT_ 128   // t-rows per block (4 waves x 32 rows)
#define UR_ 4     // rows per inner iteration (keeps LDS window reads b128-aligned)

// tanh(x) = 1 - 2/(exp(2x)+1); saturates correctly for |x| large (rcp(inf)=0)
__device__ __forceinline__ float fast_tanh(float x) {
  float p = __expf(x + x);
  float r = __builtin_amdgcn_rcpf(p + 1.0f);
  return fmaf(-2.0f, r, 1.0f);
}

__device__ __forceinline__ float4 ld4(const float* p) {
  return *(const float4*)p;
}

// Fold conv_w*loc_w -> W2[k][a]; fold query+score_b+conv_b*loc_w -> qb[b][a]
__global__ __launch_bounds__(256) void prep_kernel(
    const float* __restrict__ conv_w, const float* __restrict__ conv_b,
    const float* __restrict__ loc_w, const float* __restrict__ query,
    const float* __restrict__ score_b, float* __restrict__ W2,
    float* __restrict__ qb) {
  const int a = threadIdx.x;
  const int blk = blockIdx.x;
  if (blk < K_) {
    float acc = 0.f;
    #pragma unroll
    for (int f = 0; f < F_; ++f) acc = fmaf(conv_w[blk * F_ + f], loc_w[f * A_ + a], acc);
    W2[blk * A_ + a] = acc;
  } else {
    const int b = blk - K_;
    float acc = 0.f;
    #pragma unroll
    for (int f = 0; f < F_; ++f) acc = fmaf(conv_b[f], loc_w[f * A_ + a], acc);
    qb[b * A_ + a] = query[b * A_ + a] + score_b[a] + acc;
  }
}

// energy[b][t] = sum_a v[a] * tanh( wmem[b][t][a] + qb[b][a] + sum_k pw[b][t+k-15]*W2[k][a] )
// __launch_bounds__(256,2): cap VGPRs at 256 so the 124-reg W2 column array
// stays RESIDENT in VGPRs (at the default heuristic the compiler allocated 96
// VGPRs and re-loaded W2 from global 31x per row -> VMEM-issue-bound, 85us).
__global__ __launch_bounds__(256, 2) void energy_kernel(
    const float* __restrict__ wmem, const float* __restrict__ pw,
    const float* __restrict__ qb, const float* __restrict__ W2,
    const float* __restrict__ score_v, float* __restrict__ energy) {
  const int b = blockIdx.y;
  const int t0 = blockIdx.x * TT_;
  const int lane = threadIdx.x & 63;
  const int wv = threadIdx.x >> 6;

  __shared__ __align__(16) float lds_pw[TT_ + 36];

  // stage the pw slice for this tile (index 0 == t0-15), zero-padded (SAME conv)
  if (threadIdx.x < TT_ + 36) {
    const int g = t0 - 15 + threadIdx.x;
    lds_pw[threadIdx.x] = (g >= 0 && g < T_) ? pw[b * T_ + g] : 0.f;
  }
  __syncthreads();

  // W2 columns for this lane's 4 a-values live in VGPRs (reused for all rows)
  float4 w2c[K_];
  #pragma unroll
  for (int k = 0; k < K_; ++k) w2c[k] = ld4(W2 + k * A_ + 4 * lane);
  const float4 qb4 = ld4(qb + b * A_ + 4 * lane);
  const float4 v4  = ld4(score_v + 4 * lane);

  const float* wrow = wmem + (size_t)b * T_ * A_ + 4 * lane;
  const int rbase = 32 * wv;  // this wave's first row within the tile

  // software pipeline: prefetch the next 4-row group's wmem quads while
  // computing the current group (keeps 4KB/wave in flight over HBM latency)
  float4 w4n[UR_];
  #pragma unroll
  for (int j = 0; j < UR_; ++j) {
    const int t = t0 + rbase + j;
    const int tc = t < T_ ? t : T_ - 1;
    w4n[j] = ld4(wrow + (size_t)tc * A_);
  }

  #pragma unroll 1
  for (int i = 0; i < 32 / UR_; ++i) {
    const int widx = rbase + UR_ * i;  // 4-aligned -> b128-aligned LDS reads
    float4 w4c[UR_];
    #pragma unroll
    for (int j = 0; j < UR_; ++j) w4c[j] = w4n[j];

    // issue next group's loads before computing this group
    if (i + 1 < 32 / UR_) {
      #pragma unroll
      for (int j = 0; j < UR_; ++j) {
        const int t = t0 + widx + UR_ + j;
        const int tc = t < T_ ? t : T_ - 1;
        w4n[j] = ld4(wrow + (size_t)tc * A_);
      }
    }

    float s[36];
    #pragma unroll
    for (int m = 0; m < 9; ++m) {
      const float4 t4 = ld4(&lds_pw[widx + 4 * m]);
      s[4 * m + 0] = t4.x; s[4 * m + 1] = t4.y;
      s[4 * m + 2] = t4.z; s[4 * m + 3] = t4.w;
    }
    #pragma unroll
    for (int j = 0; j < UR_; ++j) {
      const int t = t0 + widx + j;
      const float4 w4 = w4c[j];
      float plx = 0.f, ply = 0.f, plz = 0.f, plw = 0.f;
      #pragma unroll
      for (int k = 0; k < K_; ++k) {
        const float sv = s[j + k];  // wave-uniform window scalar
        plx = fmaf(sv, w2c[k].x, plx);
        ply = fmaf(sv, w2c[k].y, ply);
        plz = fmaf(sv, w2c[k].z, plz);
        plw = fmaf(sv, w2c[k].w, plw);
      }
      const float tx = fast_tanh(w4.x + qb4.x + plx);
      const float ty = fast_tanh(w4.y + qb4.y + ply);
      const float tz = fast_tanh(w4.z + qb4.z + plz);
      const float tw = fast_tanh(w4.w + qb4.w + plw);
      float e = fmaf(v4.x, tx, fmaf(v4.y, ty, fmaf(v4.z, tz, v4.w * tw)));
      #pragma unroll
      for (int m = 1; m < 64; m <<= 1) e += __shfl_xor(e, m, 64);
      if (lane == 0 && t < T_) energy[b * T_ + t] = e;
    }
  }
}

// masked softmax over t + cumulative update; one block per batch row
__global__ __launch_bounds__(256) void softmax_kernel(
    const float* __restrict__ energy, const float* __restrict__ pw,
    const int* __restrict__ lens, float* __restrict__ out) {
  const int b = blockIdx.x;
  const int tid = threadIdx.x;
  const int len = lens[b];
  __shared__ float red[4];
  const float L2E = 1.4426950408889634f;

  // pass 1: max over valid t
  float mx = -3.4e38f;
  for (int t = tid; t < T_; t += 256)
    if (t < len) mx = fmaxf(mx, energy[b * T_ + t]);
  #pragma unroll
  for (int m = 1; m < 64; m <<= 1) mx = fmaxf(mx, __shfl_xor(mx, m, 64));
  if ((tid & 63) == 0) red[tid >> 6] = mx;
  __syncthreads();
  mx = fmaxf(fmaxf(red[0], red[1]), fmaxf(red[2], red[3]));
  __syncthreads();

  // pass 2: sum of exp
  float sm = 0.f;
  for (int t = tid; t < T_; t += 256)
    if (t < len) sm += __builtin_amdgcn_exp2f((energy[b * T_ + t] - mx) * L2E);
  #pragma unroll
  for (int m = 1; m < 64; m <<= 1) sm += __shfl_xor(sm, m, 64);
  if ((tid & 63) == 0) red[tid >> 6] = sm;
  __syncthreads();
  sm = red[0] + red[1] + red[2] + red[3];
  const float inv = 1.0f / sm;

  // pass 3: write output and new_weights
  for (int t = tid; t < T_; t += 256) {
    float o = 0.f;
    if (t < len)
      o = __builtin_amdgcn_exp2f((energy[b * T_ + t] - mx) * L2E) * inv;
    out[b * T_ + t] = o;
    out[B_ * T_ + b * T_ + t] = o + pw[b * T_ + t];
  }
}

extern "C" void kernel_launch(void* const* d_in, const int* in_sizes, int n_in,
                              void* d_out, int out_size, void* d_ws, size_t ws_size,
                              hipStream_t stream) {
  const float* query  = (const float*)d_in[0];
  const float* prev   = (const float*)d_in[1];
  const float* wmem   = (const float*)d_in[2];
  const int*   lens   = (const int*)d_in[3];
  const float* conv_w = (const float*)d_in[4];
  const float* conv_b = (const float*)d_in[5];
  const float* loc_w  = (const float*)d_in[6];
  const float* sv     = (const float*)d_in[7];
  const float* sb     = (const float*)d_in[8];
  float* out = (float*)d_out;
  float* ws  = (float*)d_ws;

  float* W2     = ws;                      // 31*256
  float* qb     = ws + K_ * A_;            // 64*256
  float* energy = ws + K_ * A_ + B_ * A_;  // 64*2000

  prep_kernel<<<K_ + B_, 256, 0, stream>>>(conv_w, conv_b, loc_w, query, sb, W2, qb);

  dim3 grid((T_ + TT_ - 1) / TT_, B_);  // 16 x 64
  energy_kernel<<<grid, 256, 0, stream>>>(wmem, prev, qb, W2, sv, energy);

  softmax_kernel<<<B_, 256, 0, stream>>>(energy, prev, lens, out);
}